// Round 1
// baseline (951.397 us; speedup 1.0000x reference)
//
#include <hip/hip_runtime.h>
#include <math.h>

#define NB 16
#define SL 2048
#define HD 64
#define TQ 16
#define BK 64
#define NT (SL / BK)          // 32 k-tiles
#define SCALE 0.125f          // 1/TEMPERATURE

typedef _Float16 half8 __attribute__((ext_vector_type(8)));
typedef float floatx4 __attribute__((ext_vector_type(4)));

__device__ __forceinline__ half8 load_frag_f32(const float* p) {
  floatx4 f0 = *(const floatx4*)p;
  floatx4 f1 = *(const floatx4*)(p + 4);
  half8 h;
  h[0] = (_Float16)f0[0]; h[1] = (_Float16)f0[1];
  h[2] = (_Float16)f0[2]; h[3] = (_Float16)f0[3];
  h[4] = (_Float16)f1[0]; h[5] = (_Float16)f1[1];
  h[6] = (_Float16)f1[2]; h[7] = (_Float16)f1[3];
  return h;
}

// One block = 16 q-rows of one batch. 256 threads = 4 waves.
// Wave w owns k-columns [16w,16w+16) of each 64-wide k-tile in QK^T,
// and d-columns [16w,16w+16) in PV.
__global__ __launch_bounds__(256) void attn_kernel(
    const float* __restrict__ Q, const float* __restrict__ K,
    const float* __restrict__ V, const int* __restrict__ DM,
    const int* __restrict__ MMk, float* __restrict__ Out,
    float* __restrict__ Attn)
{
  const int qt   = blockIdx.x;           // q-tile 0..127
  const int b    = blockIdx.y;           // batch 0..15
  const int tid  = (int)threadIdx.x;
  const int w    = tid >> 6;             // wave 0..3
  const int lane = tid & 63;
  const int quad = lane >> 4;            // 0..3
  const int nl   = lane & 15;            // 0..15

  const int qbase    = qt * TQ;
  const size_t bLD   = (size_t)b * SL * HD;
  const size_t mbase = ((size_t)b * SL + qbase) * SL;  // mask/attn row base

  __shared__ __align__(16) _Float16 ps[TQ * 72];  // p tile, stride 72 (pad)
  __shared__ float mw_s[4][16];
  __shared__ float lw_s[4][16];

  // ---- Q fragments (A operand): lane holds Q[qbase + (lane&15)][quad*8+j (+32c)]
  half8 aq0, aq1;
  {
    const float* qp = Q + bLD + (size_t)(qbase + nl) * HD + quad * 8;
    aq0 = load_frag_f32(qp);
    aq1 = load_frag_f32(qp + 32);
  }

  float mrun[4], lrun[4];
  unsigned kbits[4];
  #pragma unroll
  for (int r = 0; r < 4; ++r) { mrun[r] = -INFINITY; lrun[r] = 0.f; kbits[r] = 0u; }

  // ================= pass 1: masks + online row max/sum =================
  for (int kt = 0; kt < NT; ++kt) {
    // K fragments (B operand, gemm_bt style): lane holds K[kt*64+16w+nl][quad*8+j (+32c)]
    const float* kp = K + bLD + (size_t)(kt * BK + w * 16 + nl) * HD + quad * 8;
    half8 bk0 = load_frag_f32(kp);
    half8 bk1 = load_frag_f32(kp + 32);
    floatx4 acc = {0.f, 0.f, 0.f, 0.f};
    acc = __builtin_amdgcn_mfma_f32_16x16x32_f16(aq0, bk0, acc, 0, 0, 0);
    acc = __builtin_amdgcn_mfma_f32_16x16x32_f16(aq1, bk1, acc, 0, 0, 0);
    // C layout: lane holds S[m = quad*4+r][col = kt*64 + 16w + nl]

    const int col = kt * BK + w * 16 + nl;
    #pragma unroll
    for (int r = 0; r < 4; ++r) {
      const size_t ma = mbase + (size_t)(quad * 4 + r) * SL + col;
      const int keep = (DM[ma] != 0) && (MMk[ma] == 0);
      kbits[r] |= ((unsigned)keep) << kt;
      const float s  = acc[r] * SCALE;
      float se = keep ? s : -INFINITY;
      #pragma unroll
      for (int off = 1; off < 16; off <<= 1)
        se = fmaxf(se, __shfl_xor(se, off, 64));
      const float mn = fmaxf(mrun[r], se);
      float e = keep ? __expf(s - mn) : 0.f;
      #pragma unroll
      for (int off = 1; off < 16; off <<= 1)
        e += __shfl_xor(e, off, 64);
      const float alpha = (mn == -INFINITY) ? 1.f : __expf(mrun[r] - mn);
      lrun[r] = lrun[r] * alpha + e;
      mrun[r] = mn;
    }
  }

  // ---- merge online softmax state across the 4 waves
  if (nl == 0) {
    #pragma unroll
    for (int r = 0; r < 4; ++r) {
      mw_s[w][quad * 4 + r] = mrun[r];
      lw_s[w][quad * 4 + r] = lrun[r];
    }
  }
  __syncthreads();

  float mf[4], invl[4];
  #pragma unroll
  for (int r = 0; r < 4; ++r) {
    const int m = quad * 4 + r;
    const float M = fmaxf(fmaxf(mw_s[0][m], mw_s[1][m]), fmaxf(mw_s[2][m], mw_s[3][m]));
    float Lx = 0.f;
    #pragma unroll
    for (int ww = 0; ww < 4; ++ww) {
      const float mwv = mw_s[ww][m];
      Lx += (mwv == -INFINITY) ? 0.f : lw_s[ww][m] * __expf(mwv - M);
    }
    mf[r]   = M;
    invl[r] = (Lx > 0.f) ? (1.f / Lx) : 0.f;
  }

  // ================= pass 2: recompute S, write attn, PV =================
  floatx4 oacc = {0.f, 0.f, 0.f, 0.f};
  for (int kt = 0; kt < NT; ++kt) {
    const float* kp = K + bLD + (size_t)(kt * BK + w * 16 + nl) * HD + quad * 8;
    half8 bk0 = load_frag_f32(kp);
    half8 bk1 = load_frag_f32(kp + 32);
    floatx4 acc = {0.f, 0.f, 0.f, 0.f};
    acc = __builtin_amdgcn_mfma_f32_16x16x32_f16(aq0, bk0, acc, 0, 0, 0);
    acc = __builtin_amdgcn_mfma_f32_16x16x32_f16(aq1, bk1, acc, 0, 0, 0);

    #pragma unroll
    for (int r = 0; r < 4; ++r) {
      const int keep = (kbits[r] >> kt) & 1;
      const float p = keep ? (__expf(acc[r] * SCALE - mf[r]) * invl[r]) : 0.f;
      ps[(quad * 4 + r) * 72 + w * 16 + nl] = (_Float16)p;
    }
    __syncthreads();

    // coalesced attn stores (256B per wave-instr)
    {
      const size_t arow = mbase + (size_t)kt * BK;
      #pragma unroll
      for (int j = 0; j < 4; ++j) {
        const int idx = tid + 256 * j;        // 0..1023 = 16 rows x 64 cols
        const int rr = idx >> 6, cc = idx & 63;
        Attn[arow + (size_t)rr * SL + cc] = (float)ps[rr * 72 + cc];
      }
    }

    // P fragments (A operand) from LDS: lane holds P[lane&15][quad*8+j (+32c)]
    half8 ap0 = *(const half8*)(ps + nl * 72 + quad * 8);
    half8 ap1 = *(const half8*)(ps + nl * 72 + quad * 8 + 32);

    // V fragments (B operand) gathered from global (L2-resident):
    // lane holds V[kt*64 + quad*8 + j (+32c)][16w + nl]
    half8 bv0, bv1;
    const float* vp = V + bLD + (size_t)(kt * BK + quad * 8) * HD + w * 16 + nl;
    #pragma unroll
    for (int j = 0; j < 8; ++j) {
      bv0[j] = (_Float16)vp[(size_t)j * HD];
      bv1[j] = (_Float16)vp[(size_t)(j + 32) * HD];
    }
    oacc = __builtin_amdgcn_mfma_f32_16x16x32_f16(ap0, bv0, oacc, 0, 0, 0);
    oacc = __builtin_amdgcn_mfma_f32_16x16x32_f16(ap1, bv1, oacc, 0, 0, 0);
    __syncthreads();
  }

  // ---- output: lane holds O[m = quad*4+r][d = 16w + nl]
  {
    float* op = Out + ((size_t)b * SL + qbase) * HD;
    #pragma unroll
    for (int r = 0; r < 4; ++r)
      op[(size_t)(quad * 4 + r) * HD + w * 16 + nl] = oacc[r];
  }
}

extern "C" void kernel_launch(void* const* d_in, const int* in_sizes, int n_in,
                              void* d_out, int out_size, void* d_ws, size_t ws_size,
                              hipStream_t stream) {
  const float* Q  = (const float*)d_in[0];
  const float* K  = (const float*)d_in[1];
  const float* V  = (const float*)d_in[2];
  const int* DM   = (const int*)d_in[3];
  const int* MMk  = (const int*)d_in[4];
  float* Out  = (float*)d_out;
  float* Attn = (float*)d_out + (size_t)NB * SL * HD;  // outputs concatenated
  dim3 grid(SL / TQ, NB);
  attn_kernel<<<grid, 256, 0, stream>>>(Q, K, V, DM, MMk, Out, Attn);
}

// Round 2
// 832.798 us; speedup vs baseline: 1.1424x; 1.1424x over previous
//
#include <hip/hip_runtime.h>
#include <math.h>

#define NB 16
#define SL 2048
#define HD 64
#define TQ 16
#define BK 64
#define NT (SL / BK)          // 32 k-tiles
#define SCALE 0.125f          // 1/TEMPERATURE
#define SSTRIDE 2056          // fp16 elems per S row (2048 + 8 pad -> 4112B row stride)

typedef _Float16 half8 __attribute__((ext_vector_type(8)));
typedef float floatx4 __attribute__((ext_vector_type(4)));
typedef int intx4 __attribute__((ext_vector_type(4)));

__device__ __forceinline__ half8 load_frag_f32(const float* p) {
  floatx4 f0 = *(const floatx4*)p;
  floatx4 f1 = *(const floatx4*)(p + 4);
  half8 h;
  h[0] = (_Float16)f0[0]; h[1] = (_Float16)f0[1];
  h[2] = (_Float16)f0[2]; h[3] = (_Float16)f0[3];
  h[4] = (_Float16)f1[0]; h[5] = (_Float16)f1[1];
  h[6] = (_Float16)f1[2]; h[7] = (_Float16)f1[3];
  return h;
}

// One block = 16 q-rows of one batch, 256 threads = 4 waves.
// Phase A: QK^T once -> S (fp16) in LDS.
// Phase BC: one thread owns a 128-col chunk of one row: coalesced int4 mask
//           loads, masked max (one shuffle-reduce), exp+sum (one reduce).
// Phase D: attn stores from registers, then PV MFMA on unnormalized p.
__global__ __launch_bounds__(256) void attn_kernel(
    const float* __restrict__ Q, const float* __restrict__ K,
    const float* __restrict__ V, const int* __restrict__ DM,
    const int* __restrict__ MMk, float* __restrict__ Out,
    float* __restrict__ Attn)
{
  const int qt   = blockIdx.x;           // q-tile 0..127
  const int b    = blockIdx.y;           // batch 0..15
  const int tid  = (int)threadIdx.x;
  const int w    = tid >> 6;             // wave 0..3
  const int lane = tid & 63;
  const int quad = lane >> 4;            // 0..3
  const int nl   = lane & 15;            // 0..15
  const int row16 = tid >> 4;            // 0..15  (row this thread owns in BC/D1)
  const int ci    = tid & 15;            // col-chunk index within the row

  const int qbase    = qt * TQ;
  const size_t bLD   = (size_t)b * SL * HD;
  const size_t mbase = ((size_t)b * SL + qbase) * SL;  // mask/attn row base

  __shared__ __align__(16) _Float16 S[TQ * SSTRIDE];   // 65792 B
  __shared__ float sinv_s[TQ];

  // ---- Q fragments (A operand): lane holds Q[qbase + nl][quad*8+j (+32)]
  half8 aq0, aq1;
  {
    const float* qp = Q + bLD + (size_t)(qbase + nl) * HD + quad * 8;
    aq0 = load_frag_f32(qp);
    aq1 = load_frag_f32(qp + 32);
  }

  // ================= Phase A: QK^T -> S in LDS =================
  #pragma unroll 2
  for (int kt = 0; kt < NT; ++kt) {
    const float* kp = K + bLD + (size_t)(kt * BK + w * 16 + nl) * HD + quad * 8;
    half8 bk0 = load_frag_f32(kp);
    half8 bk1 = load_frag_f32(kp + 32);
    floatx4 acc = {0.f, 0.f, 0.f, 0.f};
    acc = __builtin_amdgcn_mfma_f32_16x16x32_f16(aq0, bk0, acc, 0, 0, 0);
    acc = __builtin_amdgcn_mfma_f32_16x16x32_f16(aq1, bk1, acc, 0, 0, 0);
    // C layout: lane holds S[row = quad*4+r][col = kt*64 + w*16 + nl]
    const int col = kt * BK + w * 16 + nl;
    #pragma unroll
    for (int r = 0; r < 4; ++r)
      S[(quad * 4 + r) * SSTRIDE + col] = (_Float16)(acc[r] * SCALE);
  }
  __syncthreads();

  // ================= Phase BC: mask + max, exp + sum =================
  const int* dmr = DM  + mbase + (size_t)row16 * SL;
  const int* mkr = MMk + mbase + (size_t)row16 * SL;

  half8 sv[16];                 // this thread's 128 columns, fp16
  float mx = -INFINITY;
  #pragma unroll 4
  for (int it = 0; it < 16; ++it) {
    const int c = it * 128 + ci * 8;
    intx4 d0 = *(const intx4*)(dmr + c);
    intx4 d1 = *(const intx4*)(dmr + c + 4);
    intx4 m0 = *(const intx4*)(mkr + c);
    intx4 m1 = *(const intx4*)(mkr + c + 4);
    half8 s8 = *(const half8*)(&S[row16 * SSTRIDE + c]);
    #pragma unroll
    for (int j = 0; j < 4; ++j) {
      const bool k0 = (d0[j] != 0) && (m0[j] == 0);
      const bool k1 = (d1[j] != 0) && (m1[j] == 0);
      float s0 = k0 ? (float)s8[j]     : -INFINITY;
      float s1 = k1 ? (float)s8[j + 4] : -INFINITY;
      mx = fmaxf(mx, fmaxf(s0, s1));
      s8[j]     = (_Float16)s0;
      s8[j + 4] = (_Float16)s1;
    }
    sv[it] = s8;
  }
  // row max across the 16 chunk-threads (consecutive lanes in one wave)
  #pragma unroll
  for (int off = 1; off < 16; off <<= 1)
    mx = fmaxf(mx, __shfl_xor(mx, off, 64));

  float sum = 0.f;
  #pragma unroll 4
  for (int it = 0; it < 16; ++it) {
    half8 s8 = sv[it];
    half8 p8;
    #pragma unroll
    for (int j = 0; j < 8; ++j) {
      const float s = (float)s8[j];
      const float e = (s > -1e30f) ? __expf(s - mx) : 0.f;  // masked -> 0, no NaN
      sum += e;
      p8[j] = (_Float16)e;      // e <= 1, fp16 safe
    }
    sv[it] = p8;
    *(half8*)(&S[row16 * SSTRIDE + it * 128 + ci * 8]) = p8;  // p_unnorm for PV
  }
  #pragma unroll
  for (int off = 1; off < 16; off <<= 1)
    sum += __shfl_xor(sum, off, 64);
  const float is = (sum > 0.f) ? 1.f / sum : 0.f;
  if (ci == 0) sinv_s[row16] = is;

  // ================= Phase D1: attn stores (from registers) =================
  float* arow = Attn + mbase + (size_t)row16 * SL;
  #pragma unroll 2
  for (int it = 0; it < 16; ++it) {
    half8 p8 = sv[it];
    floatx4 o0, o1;
    #pragma unroll
    for (int j = 0; j < 4; ++j) {
      o0[j] = (float)p8[j]     * is;
      o1[j] = (float)p8[j + 4] * is;
    }
    *(floatx4*)(arow + it * 128 + ci * 8)     = o0;
    *(floatx4*)(arow + it * 128 + ci * 8 + 4) = o1;
  }
  __syncthreads();   // all p in LDS + sinv_s visible before PV

  // ================= Phase D2: PV MFMA =================
  floatx4 oacc = {0.f, 0.f, 0.f, 0.f};
  #pragma unroll 2
  for (int kt = 0; kt < NT; ++kt) {
    // A operand: lane holds P[m = nl][k = kt*64 + quad*8 + j (+32)]
    half8 ap0 = *(const half8*)(&S[nl * SSTRIDE + kt * BK + quad * 8]);
    half8 ap1 = *(const half8*)(&S[nl * SSTRIDE + kt * BK + quad * 8 + 32]);
    // B operand: lane holds V[k = kt*64 + quad*8 + j (+32)][n = w*16 + nl]
    half8 bv0, bv1;
    const float* vp = V + bLD + (size_t)(kt * BK + quad * 8) * HD + w * 16 + nl;
    #pragma unroll
    for (int j = 0; j < 8; ++j) {
      bv0[j] = (_Float16)vp[(size_t)j * HD];
      bv1[j] = (_Float16)vp[(size_t)(j + 32) * HD];
    }
    oacc = __builtin_amdgcn_mfma_f32_16x16x32_f16(ap0, bv0, oacc, 0, 0, 0);
    oacc = __builtin_amdgcn_mfma_f32_16x16x32_f16(ap1, bv1, oacc, 0, 0, 0);
  }

  // O[m = quad*4+r][d = w*16 + nl], scale by 1/l of that row
  {
    float* op = Out + ((size_t)b * SL + qbase) * HD;
    #pragma unroll
    for (int r = 0; r < 4; ++r)
      op[(size_t)(quad * 4 + r) * HD + w * 16 + nl] = oacc[r] * sinv_s[quad * 4 + r];
  }
}

extern "C" void kernel_launch(void* const* d_in, const int* in_sizes, int n_in,
                              void* d_out, int out_size, void* d_ws, size_t ws_size,
                              hipStream_t stream) {
  const float* Q  = (const float*)d_in[0];
  const float* K  = (const float*)d_in[1];
  const float* V  = (const float*)d_in[2];
  const int* DM   = (const int*)d_in[3];
  const int* MMk  = (const int*)d_in[4];
  float* Out  = (float*)d_out;
  float* Attn = (float*)d_out + (size_t)NB * SL * HD;  // outputs concatenated
  dim3 grid(SL / TQ, NB);
  attn_kernel<<<grid, 256, 0, stream>>>(Q, K, V, DM, MMk, Out, Attn);
}

// Round 3
// 760.472 us; speedup vs baseline: 1.2511x; 1.0951x over previous
//
#include <hip/hip_runtime.h>
#include <math.h>

#define NB 16
#define SL 2048
#define HD 64
#define TQ 16
#define BK 64
#define NT (SL / BK)          // 32 k-tiles
#define SCALE 0.125f          // 1/TEMPERATURE
#define SSTRIDE 2056          // fp16 elems per S row (2048 + 8 pad)

typedef _Float16 half8 __attribute__((ext_vector_type(8)));
typedef float floatx4 __attribute__((ext_vector_type(4)));
typedef int intx4 __attribute__((ext_vector_type(4)));

__device__ __forceinline__ half8 load_frag_f32(const float* p) {
  floatx4 f0 = *(const floatx4*)p;
  floatx4 f1 = *(const floatx4*)(p + 4);
  half8 h;
  h[0] = (_Float16)f0[0]; h[1] = (_Float16)f0[1];
  h[2] = (_Float16)f0[2]; h[3] = (_Float16)f0[3];
  h[4] = (_Float16)f1[0]; h[5] = (_Float16)f1[1];
  h[6] = (_Float16)f1[2]; h[7] = (_Float16)f1[3];
  return h;
}

// One block = 16 q-rows of one batch, 256 threads = 4 waves.
// A: QK^T -> S (fp16, LDS). BC: 3 LDS passes per row-chunk (mask+max / exp+sum
// / scale+store), no per-thread arrays (round-2 spill fix). D2: PV MFMA.
__global__ __launch_bounds__(256) void attn_kernel(
    const float* __restrict__ Q, const float* __restrict__ K,
    const float* __restrict__ V, const int* __restrict__ DM,
    const int* __restrict__ MMk, float* __restrict__ Out,
    float* __restrict__ Attn)
{
  const int qt   = blockIdx.x;           // q-tile 0..127
  const int b    = blockIdx.y;           // batch 0..15
  const int tid  = (int)threadIdx.x;
  const int w    = tid >> 6;             // wave 0..3
  const int lane = tid & 63;
  const int quad = lane >> 4;            // 0..3
  const int nl   = lane & 15;            // 0..15
  const int row16 = tid >> 4;            // row this thread owns in BC
  const int ci    = tid & 15;            // col-chunk index within the row

  const int qbase    = qt * TQ;
  const size_t bLD   = (size_t)b * SL * HD;
  const size_t mbase = ((size_t)b * SL + qbase) * SL;

  __shared__ __align__(16) _Float16 S[TQ * SSTRIDE];   // ~65.8 KB
  __shared__ float sinv_s[TQ];

  // ---- Q fragments (A operand): lane holds Q[qbase + nl][quad*8+j (+32)]
  half8 aq0, aq1;
  {
    const float* qp = Q + bLD + (size_t)(qbase + nl) * HD + quad * 8;
    aq0 = load_frag_f32(qp);
    aq1 = load_frag_f32(qp + 32);
  }

  // ================= Phase A: QK^T -> S in LDS =================
  #pragma unroll 2
  for (int kt = 0; kt < NT; ++kt) {
    const float* kp = K + bLD + (size_t)(kt * BK + w * 16 + nl) * HD + quad * 8;
    half8 bk0 = load_frag_f32(kp);
    half8 bk1 = load_frag_f32(kp + 32);
    floatx4 acc = {0.f, 0.f, 0.f, 0.f};
    acc = __builtin_amdgcn_mfma_f32_16x16x32_f16(aq0, bk0, acc, 0, 0, 0);
    acc = __builtin_amdgcn_mfma_f32_16x16x32_f16(aq1, bk1, acc, 0, 0, 0);
    const int col = kt * BK + w * 16 + nl;
    #pragma unroll
    for (int r = 0; r < 4; ++r)
      S[(quad * 4 + r) * SSTRIDE + col] = (_Float16)(acc[r] * SCALE);
  }
  __syncthreads();

  // ================= P1: masks + thread-local max (in-place) =================
  const int* dmr = DM  + mbase + (size_t)row16 * SL;
  const int* mkr = MMk + mbase + (size_t)row16 * SL;
  _Float16* srow = &S[row16 * SSTRIDE];

  float mx = -INFINITY;
  #pragma unroll 8
  for (int it = 0; it < 16; ++it) {
    const int c = it * 128 + ci * 8;
    intx4 d0 = __builtin_nontemporal_load((const intx4*)(dmr + c));
    intx4 d1 = __builtin_nontemporal_load((const intx4*)(dmr + c + 4));
    intx4 m0 = __builtin_nontemporal_load((const intx4*)(mkr + c));
    intx4 m1 = __builtin_nontemporal_load((const intx4*)(mkr + c + 4));
    half8 s8 = *(const half8*)(srow + c);
    #pragma unroll
    for (int j = 0; j < 4; ++j) {
      const bool k0 = (d0[j] != 0) && (m0[j] == 0);
      const bool k1 = (d1[j] != 0) && (m1[j] == 0);
      float s0 = k0 ? (float)s8[j]     : -INFINITY;
      float s1 = k1 ? (float)s8[j + 4] : -INFINITY;
      mx = fmaxf(mx, fmaxf(s0, s1));
      s8[j]     = (_Float16)s0;
      s8[j + 4] = (_Float16)s1;
    }
    *(half8*)(srow + c) = s8;
  }
  #pragma unroll
  for (int off = 1; off < 16; off <<= 1)
    mx = fmaxf(mx, __shfl_xor(mx, off, 64));

  // ================= P2: exp + sum (in-place) =================
  float sum = 0.f;
  #pragma unroll 4
  for (int it = 0; it < 16; ++it) {
    const int c = it * 128 + ci * 8;
    half8 s8 = *(const half8*)(srow + c);
    half8 p8;
    #pragma unroll
    for (int j = 0; j < 8; ++j) {
      const float s = (float)s8[j];
      const float e = (s > -1e30f) ? __expf(s - mx) : 0.f;
      sum += e;
      p8[j] = (_Float16)e;     // e <= 1, fp16 safe
    }
    *(half8*)(srow + c) = p8;  // unnormalized p for PV
  }
  #pragma unroll
  for (int off = 1; off < 16; off <<= 1)
    sum += __shfl_xor(sum, off, 64);
  const float is = (sum > 0.f) ? 1.f / sum : 0.f;
  if (ci == 0) sinv_s[row16] = is;

  // ================= P3: normalized attn stores (nontemporal) =================
  float* arow = Attn + mbase + (size_t)row16 * SL;
  #pragma unroll 4
  for (int it = 0; it < 16; ++it) {
    const int c = it * 128 + ci * 8;
    half8 p8 = *(const half8*)(srow + c);
    floatx4 o0, o1;
    #pragma unroll
    for (int j = 0; j < 4; ++j) {
      o0[j] = (float)p8[j]     * is;
      o1[j] = (float)p8[j + 4] * is;
    }
    __builtin_nontemporal_store(o0, (floatx4*)(arow + c));
    __builtin_nontemporal_store(o1, (floatx4*)(arow + c + 4));
  }
  __syncthreads();   // p in LDS + sinv_s visible before PV

  // ================= Phase D2: PV MFMA =================
  floatx4 oacc = {0.f, 0.f, 0.f, 0.f};
  #pragma unroll 2
  for (int kt = 0; kt < NT; ++kt) {
    // A operand: lane holds P[m = nl][k = kt*64 + quad*8 + j (+32)]
    half8 ap0 = *(const half8*)(&S[nl * SSTRIDE + kt * BK + quad * 8]);
    half8 ap1 = *(const half8*)(&S[nl * SSTRIDE + kt * BK + quad * 8 + 32]);
    // B operand: lane holds V[k = kt*64 + quad*8 + j (+32)][n = w*16 + nl]
    half8 bv0, bv1;
    const float* vp = V + bLD + (size_t)(kt * BK + quad * 8) * HD + w * 16 + nl;
    #pragma unroll
    for (int j = 0; j < 8; ++j) {
      bv0[j] = (_Float16)vp[(size_t)j * HD];
      bv1[j] = (_Float16)vp[(size_t)(j + 32) * HD];
    }
    oacc = __builtin_amdgcn_mfma_f32_16x16x32_f16(ap0, bv0, oacc, 0, 0, 0);
    oacc = __builtin_amdgcn_mfma_f32_16x16x32_f16(ap1, bv1, oacc, 0, 0, 0);
  }

  // O[m = quad*4+r][d = w*16 + nl], scale by 1/l
  {
    float* op = Out + ((size_t)b * SL + qbase) * HD;
    #pragma unroll
    for (int r = 0; r < 4; ++r)
      op[(size_t)(quad * 4 + r) * HD + w * 16 + nl] = oacc[r] * sinv_s[quad * 4 + r];
  }
}

extern "C" void kernel_launch(void* const* d_in, const int* in_sizes, int n_in,
                              void* d_out, int out_size, void* d_ws, size_t ws_size,
                              hipStream_t stream) {
  const float* Q  = (const float*)d_in[0];
  const float* K  = (const float*)d_in[1];
  const float* V  = (const float*)d_in[2];
  const int* DM   = (const int*)d_in[3];
  const int* MMk  = (const int*)d_in[4];
  float* Out  = (float*)d_out;
  float* Attn = (float*)d_out + (size_t)NB * SL * HD;
  dim3 grid(SL / TQ, NB);
  attn_kernel<<<grid, 256, 0, stream>>>(Q, K, V, DM, MMk, Out, Attn);
}